// Round 3
// baseline (266.748 us; speedup 1.0000x reference)
//
#include <hip/hip_runtime.h>
#include <math.h>

// Attention pooling: context[b,d] = sum_t softmax_t( V . tanh(full[b,t,:]@W1 + last[b,:]@W2 + b1+b2) ) * full[b,t,d]
// B=32 T=2048 D=512 U=512, fp32 in/out. bV softmax-invariant -> dropped; b1+b2 folded into h2.
// R10: occupancy attack (Guideline 1). R7-R9 were pinned at 8 waves/CU by REGISTERS:
//   acc[4][8]=128 + ~120 VGPR = ~248 of the unified 512-per-2-waves file -> 2 waves/SIMD,
//   so every vmcnt/barrier wait had no TLP cover (why T3/T4 restructures were ~null).
//   Now: 1024 thr / 16 waves, wave tile 64x64 (acc[4][4]=64 regs), A reg-staged to LDS as
//   bf16 (load f32x4 -> f2bf once -> ds_write_b64; K-loop reads bf16 frags directly, no
//   f32 temps, no duplicated cvt). B keeps global_load_lds + counted-vmcnt 2-ahead.
//   Target <=128 total regs/wave -> 4 waves/SIMD -> 16 waves/CU.
// ws (floats): h2 [B*U] @0, m_arr [512] @16384, l_arr [512] @16896, ctx [B*16*D] @17408,
//              W1T [U*D] bf16 @ float-offset 279552. Total ~1.64 MB.

#define BB 32
#define TT 2048
#define DD 512
#define UU 512
#define BKK 32
#define KSTEPS 16

typedef short bf16x8 __attribute__((ext_vector_type(8)));
typedef short s16x4  __attribute__((ext_vector_type(4)));
typedef float f32x4  __attribute__((ext_vector_type(4)));

static __device__ __forceinline__ short f2bf(float f) {
    unsigned x = __float_as_uint(f);
    return (short)((x + 0x7fffu + ((x >> 16) & 1u)) >> 16);   // RNE
}

static __device__ __forceinline__ float fast_tanh(float x) {
    float e = __expf(2.f * x);
    return 1.f - 2.f * __builtin_amdgcn_rcpf(e + 1.f);
}

// ---------------- prep ----------------
// blocks [0,256): W1T[u][d] = bf16(W1[d][u]) tile-transposed
// blocks [256,384): h2 slice — block owns (b, 128-u-slice); threads d-split x2 + LDS combine
__global__ __launch_bounds__(256) void prep_kernel(const float* __restrict__ W1,
                                                   short* __restrict__ W1T,
                                                   const float* __restrict__ last,
                                                   const float* __restrict__ W2,
                                                   const float* __restrict__ b1,
                                                   const float* __restrict__ b2,
                                                   float* __restrict__ h2) {
    __shared__ float tile[32][33];
    __shared__ float ls[DD];
    __shared__ float part[256];
    const int bid = blockIdx.x;
    const int tid = threadIdx.x;
    if (bid < 256) {
        const int tr = (bid >> 4) << 5;   // d-block origin
        const int tc = (bid & 15) << 5;   // u-block origin
#pragma unroll
        for (int p = 0; p < 4; ++p) {
            const int r = p * 8 + (tid >> 5), c = tid & 31;
            tile[r][c] = W1[(size_t)(tr + r) * UU + tc + c];
        }
        __syncthreads();
#pragma unroll
        for (int p = 0; p < 4; ++p) {
            const int r = p * 8 + (tid >> 5), c = tid & 31;    // r=u-local, c=d-local
            W1T[(size_t)(tc + r) * DD + tr + c] = f2bf(tile[c][r]);
        }
    } else {
        const int b2i = bid - 256;
        const int b  = b2i >> 2;
        const int u0 = (b2i & 3) << 7;
        for (int i = tid; i < DD; i += 256) ls[i] = last[b * DD + i];
        __syncthreads();
        const int uu = tid & 127;
        const int dh = tid >> 7;
        float acc = 0.f;
#pragma unroll 8
        for (int d = dh * 256; d < dh * 256 + 256; ++d)
            acc += ls[d] * W2[d * UU + u0 + uu];
        part[tid] = acc;
        __syncthreads();
        if (tid < 128) {
            const int u = u0 + tid;
            h2[b * UU + u] = part[tid] + part[tid + 128] + b1[u] + b2[u];
        }
    }
}

// ---------------- score + partial context (flash-style) ----------------
// 512 blocks: b = bid>>4, tile = bid&15, t0 = tile*128. 1024 threads = 16 waves, 2(M) x 8(N);
// wave tile 64x64 (4 mt x 4 nt, acc=64 regs). K-loop BK=32 (16 steps):
//   P1 ds_read af[4](bf16 A) + bfr[4](B) from buf[cur]
//   P2 lgkmcnt(0) + sched_barrier + s_barrier          [buf cur fully consumed]
//   P3 vmcnt(2) -> ds_write A(ko+1) (staged regs) into a16[cur^1]
//   P4 global_load f32x4 A(ko+2) -> ping-pong reg      [1 instr/thread]
//   P5 global_load_lds B(ko+2) -> blds[cur]            [2 instrs/thread]
//   P6 16 MFMA
//   P7 vmcnt(3) [B(ko+1) landed] + lgkmcnt(0) [my ds_write] + s_barrier
// A LDS layout: row 64B (32 bf16), 16B chunks xor-swizzled chunk' = q ^ (r&3).
// B LDS layout: as R9, slot(u,kc)=u*4+(kc^((u>>1)&3)) bf16x8 chunks.
// Epilogue: tanh+V dot (8-way u-split) -> softmax stats -> partial ctx from L2-hot tile.
__global__ __launch_bounds__(1024, 4) void score_kernel(const float* __restrict__ full,
                                                        const short* __restrict__ W1T,
                                                        const float* __restrict__ h2,
                                                        const float* __restrict__ V,
                                                        float* __restrict__ ctx,
                                                        float* __restrict__ m_arr,
                                                        float* __restrict__ l_arr) {
    __shared__ __align__(16) short a16[2][128 * 32];     // 2 x 8 KB bf16 A tile
    __shared__ __align__(16) short blds[2][512 * 32];    // 2 x 32 KB bf16 B tile
    __shared__ float red64[16][64];
    __shared__ float esc[128];
    __shared__ float sred[8];
    __shared__ __align__(16) float red4[8][128][4];      // 16 KB

    const int bid = blockIdx.x;
    const int b    = bid >> 4;
    const int t0   = (bid & 15) << 7;
    const int tid  = threadIdx.x;
    const int w    = tid >> 6;
    const int lane = tid & 63;
    const int quad = lane >> 4;
    const int col  = lane & 15;
    const int wm   = w >> 3;          // 0..1
    const int wn   = w & 7;           // 0..7

    f32x4 acc[4][4];
#pragma unroll
    for (int i = 0; i < 4; ++i)
#pragma unroll
        for (int j = 0; j < 4; ++j) acc[i][j] = (f32x4){0.f, 0.f, 0.f, 0.f};

    const size_t fullbase = (size_t)(b * TT + t0) * DD;

    // ---- A reg-staging mapping: thread -> (row sr, 4-float group se) ----
    const int sr = tid >> 3;          // 0..127
    const int se = tid & 7;           // 0..7 -> floats se*4..se*4+3
    const float* aSrc = &full[fullbase + (size_t)sr * DD + se * 4];
    // swizzled LDS write offset (shorts): chunk = se>>1 -> chunk^(sr&3); half = se&1
    const int awOff = sr * 32 + ((((se >> 1) ^ (sr & 3)) << 3) + ((se & 1) << 2));

    // ---- B DMA: 2048 bf16x8 chunks, 2 issues/thread ----
#define STAGE_B(bufidx, koidx) do {                                                   \
        _Pragma("unroll")                                                             \
        for (int i = 0; i < 2; ++i) {                                                 \
            const int sb = w * 128 + i * 64;                                          \
            const int s  = sb + lane;                                                 \
            const int u  = s >> 2;                                                    \
            const int kc = (s & 3) ^ ((u >> 1) & 3);                                  \
            const short* g = &W1T[(size_t)u * DD + (koidx) * BKK + kc * 8];           \
            __builtin_amdgcn_global_load_lds(                                         \
                (const __attribute__((address_space(1))) void*)g,                     \
                (__attribute__((address_space(3))) void*)&blds[bufidx][sb * 8], 16, 0, 0); \
        }                                                                             \
    } while (0)

#define CVT_WRITE(buf, ar) do {                                                       \
        s16x4 q_ = (s16x4){f2bf((ar).x), f2bf((ar).y), f2bf((ar).z), f2bf((ar).w)};   \
        *(s16x4*)&a16[buf][awOff] = q_;                                               \
    } while (0)

    // ---- prologue: A(0),A(1) loads; B(0),B(1) DMA; write A(0); wait B(0) ----
    f32x4 aregA = *(const f32x4*)(aSrc + 0 * BKK);       // A(0)
    f32x4 aregB = *(const f32x4*)(aSrc + 1 * BKK);       // A(1)
    STAGE_B(0, 0);
    STAGE_B(1, 1);
    asm volatile("s_waitcnt vmcnt(5)" ::: "memory");     // A(0) landed
    CVT_WRITE(0, aregA);
    asm volatile("s_waitcnt vmcnt(2)" ::: "memory");     // B(0) landed (B(1) flying)
    asm volatile("s_waitcnt lgkmcnt(0)" ::: "memory");   // my ds_write drained
    __builtin_amdgcn_s_barrier();

    for (int ko = 0; ko < KSTEPS; ++ko) {
        const int cur = ko & 1;
        // ---- P1: ds_read fragments from buf[cur] ----
        bf16x8 af[4], bfr[4];
#pragma unroll
        for (int mt = 0; mt < 4; ++mt) {
            const int r = wm * 64 + mt * 16 + col;
            af[mt] = *(const bf16x8*)&a16[cur][r * 32 + ((quad ^ (r & 3)) << 3)];
        }
#pragma unroll
        for (int nt = 0; nt < 4; ++nt) {
            const int u = wn * 64 + nt * 16 + col;
            bfr[nt] = *(const bf16x8*)&blds[cur][(u * 4 + (quad ^ ((u >> 1) & 3))) * 8];
        }
        asm volatile("s_waitcnt lgkmcnt(0)" ::: "memory");
        __builtin_amdgcn_sched_barrier(0);               // rule 18
        __builtin_amdgcn_s_barrier();                    // buf[cur] consumed by all

        // ---- P3: write A(ko+1) into a16[cur^1] ----
        if (ko + 1 < KSTEPS) {
            asm volatile("s_waitcnt vmcnt(2)" ::: "memory");  // A(ko+1) landed
            if (ko & 1) CVT_WRITE(cur ^ 1, aregA);
            else        CVT_WRITE(cur ^ 1, aregB);
        }
        // ---- P4: issue A(ko+2) global load into freed reg ----
        if (ko + 2 < KSTEPS) {
            if (ko & 1) aregB = *(const f32x4*)(aSrc + (ko + 2) * BKK);
            else        aregA = *(const f32x4*)(aSrc + (ko + 2) * BKK);
        }
        // ---- P5: issue B(ko+2) DMA into blds[cur] ----
        if (ko + 2 < KSTEPS) STAGE_B(cur, ko + 2);

        // ---- P6: MFMA ----
#pragma unroll
        for (int nt = 0; nt < 4; ++nt)
#pragma unroll
            for (int mt = 0; mt < 4; ++mt)
                acc[mt][nt] = __builtin_amdgcn_mfma_f32_16x16x32_bf16(af[mt], bfr[nt], acc[mt][nt], 0, 0, 0);

        // ---- P7: counted wait for B(ko+1); drain my ds_write; barrier ----
        if (ko < KSTEPS - 2) {
            asm volatile("s_waitcnt vmcnt(3)" ::: "memory");
        } else if (ko == KSTEPS - 2) {
            asm volatile("s_waitcnt vmcnt(0)" ::: "memory");
        }
        if (ko < KSTEPS - 1) {
            asm volatile("s_waitcnt lgkmcnt(0)" ::: "memory");
            __builtin_amdgcn_s_barrier();
        }
    }
#undef STAGE_B
#undef CVT_WRITE

    // ---- raw scores: tanh + V-dot over this wave's 64 u, reduce cols, then over wn ----
    float srow[16];
#pragma unroll
    for (int i = 0; i < 16; ++i) srow[i] = 0.f;
#pragma unroll
    for (int nt = 0; nt < 4; ++nt) {
        const int u = wn * 64 + nt * 16 + col;
        const float hv = h2[b * UU + u];
        const float vv = V[u];
#pragma unroll
        for (int mt = 0; mt < 4; ++mt)
#pragma unroll
            for (int r = 0; r < 4; ++r)
                srow[mt * 4 + r] += fast_tanh(acc[mt][nt][r] + hv) * vv;
    }
#pragma unroll
    for (int off = 1; off < 16; off <<= 1) {
#pragma unroll
        for (int i = 0; i < 16; ++i) srow[i] += __shfl_xor(srow[i], off, 64);
    }
    if (col == 0) {
#pragma unroll
        for (int mt = 0; mt < 4; ++mt)
#pragma unroll
            for (int r = 0; r < 4; ++r)
                red64[w][mt * 16 + quad * 4 + r] = srow[mt * 4 + r];
    }
    __syncthreads();

    // ---- softmax stats over 128 rows (threads 0..127 = waves 0,1) ----
    float sv = 0.f;
    if (tid < 128) {
        const int wmX = tid >> 6, rr = tid & 63;
#pragma unroll
        for (int j = 0; j < 8; ++j) sv += red64[wmX * 8 + j][rr];
        float mv = sv;
#pragma unroll
        for (int off = 1; off < 64; off <<= 1) mv = fmaxf(mv, __shfl_xor(mv, off, 64));
        if (lane == 0) sred[w] = mv;
    }
    __syncthreads();
    const float M = fmaxf(sred[0], sred[1]);
    if (tid < 128) {
        float e = __expf(sv - M);
        esc[tid] = e;
#pragma unroll
        for (int off = 1; off < 64; off <<= 1) e += __shfl_xor(e, off, 64);
        if (lane == 0) sred[4 + w] = e;
    }
    __syncthreads();
    if (tid == 0) { m_arr[bid] = M; l_arr[bid] = sred[4] + sred[5]; }

    // ---- partial context from the (L2-hot) tile: ctx[d] = sum_t esc[t] * full[t,d] ----
    const int c  = tid & 127;             // float4 column, d = c*4
    const int tp = tid >> 7;              // t residue mod 8
    float ax = 0.f, ay = 0.f, az = 0.f, aw = 0.f;
#pragma unroll 4
    for (int i = 0; i < 16; ++i) {
        const int t = i * 8 + tp;
        const float4 v = *(const float4*)&full[fullbase + (size_t)t * DD + c * 4];
        const float e = esc[t];
        ax += e * v.x; ay += e * v.y; az += e * v.z; aw += e * v.w;
    }
    *(float4*)&red4[tp][c][0] = make_float4(ax, ay, az, aw);
    __syncthreads();
    if (tp == 0) {
        float4 s = make_float4(0.f, 0.f, 0.f, 0.f);
#pragma unroll
        for (int j = 0; j < 8; ++j) {
            const float4 p = *(const float4*)&red4[j][c][0];
            s.x += p.x; s.y += p.y; s.z += p.z; s.w += p.w;
        }
        *(float4*)&ctx[(size_t)bid * DD + c * 4] = s;
    }
}

// ---------------- combine: out[b,d] = sum_i w_i*ctx[b,i,d] / sum_i w_i*l_i, w_i = e^{m_i - M} ----------------
__global__ __launch_bounds__(256) void combine_kernel(const float* __restrict__ ctx,
                                                      const float* __restrict__ m_arr,
                                                      const float* __restrict__ l_arr,
                                                      float* __restrict__ out) {
    const int b = blockIdx.x;
    const int tid = threadIdx.x;
    __shared__ float wgt[16];
    __shared__ float linv;
    if (tid == 0) {
        float M = -1e30f;
#pragma unroll
        for (int i = 0; i < 16; ++i) M = fmaxf(M, m_arr[b * 16 + i]);
        float l = 0.f;
#pragma unroll
        for (int i = 0; i < 16; ++i) {
            wgt[i] = __expf(m_arr[b * 16 + i] - M);
            l += wgt[i] * l_arr[b * 16 + i];
        }
        linv = 1.f / l;
    }
    __syncthreads();
    float s0 = 0.f, s1 = 0.f;
#pragma unroll
    for (int i = 0; i < 16; ++i) {
        const float wi = wgt[i];
        const float* cp = &ctx[(size_t)(b * 16 + i) * DD + tid * 2];
        s0 += wi * cp[0];
        s1 += wi * cp[1];
    }
    out[b * DD + tid * 2]     = s0 * linv;
    out[b * DD + tid * 2 + 1] = s1 * linv;
}

extern "C" void kernel_launch(void* const* d_in, const int* in_sizes, int n_in,
                              void* d_out, int out_size, void* d_ws, size_t ws_size,
                              hipStream_t stream) {
    const float* full = (const float*)d_in[0];
    const float* last = (const float*)d_in[1];
    const float* W1   = (const float*)d_in[2];
    const float* b1   = (const float*)d_in[3];
    const float* W2   = (const float*)d_in[4];
    const float* b2   = (const float*)d_in[5];
    const float* V    = (const float*)d_in[6];
    // d_in[7] = bV: softmax-invariant, unused.

    float* out   = (float*)d_out;
    float* h2    = (float*)d_ws;                    // 16384 floats
    float* m_arr = h2 + (size_t)BB * UU;            // 512
    float* l_arr = m_arr + 512;                     // 512
    float* ctx   = l_arr + 512;                     // 32*16*512 = 262144
    short* W1T   = (short*)(ctx + (size_t)BB * 16 * DD);  // U*D bf16

    prep_kernel<<<384, 256, 0, stream>>>(W1, W1T, last, W2, b1, b2, h2);
    score_kernel<<<BB * 16, 1024, 0, stream>>>(full, W1T, h2, V, ctx, m_arr, l_arr);
    combine_kernel<<<BB, 256, 0, stream>>>(ctx, m_arr, l_arr, out);
}